// Round 9
// baseline (37.261 us; speedup 1.0000x reference)
//
#include <hip/hip_runtime.h>

#define BB 16
#define HH 2048
#define NN 1024
#define DD 2048
#define DG4 (DD / 4)   // 512 float4-groups per row

// Workspace: unsigned flag @0 (memset per replay); int hdr[32] @128;
// wsB[DG4][BB] u64 @256 — 4 consecutive d as packed bf16x4 per batch (64 KB).

__device__ __forceinline__ unsigned short f2bf(float f) {
    unsigned u = __float_as_uint(f);
    u += 0x7fffu + ((u >> 16) & 1u);   // round-to-nearest-even
    return (unsigned short)(u >> 16);
}

// Single fused kernel: 256 blocks x 512 threads, <=29 KB LDS -> 1 block/CU,
// all blocks resident. Blocks 0..15 produce ws for batch g (agent-scope
// stores -> coherent point), release flag; all blocks consume at flag==16.
// Producers do NOT prefetch: keeps their z/W critical path + barriers clean.
__global__ __launch_bounds__(512) void ot_one(const int* __restrict__ z,
                                              const float* __restrict__ Fm,
                                              const float* __restrict__ Vm,
                                              const float* __restrict__ Wm,
                                              unsigned* __restrict__ flag,
                                              int* __restrict__ hdr,
                                              unsigned long long* __restrict__ wsB,
                                              float* __restrict__ out) {
    __shared__ int   zsh[HH];            // 8 KB (producer only)
    __shared__ float u[DD];              // 8 KB (producer only)
    __shared__ float wsf[DD];            // 8 KB (producer only)
    __shared__ float redt[8];
    __shared__ float red[8][8][BB];      // 4 KB

    const int tid  = threadIdx.x;
    const int lane = tid & 63;
    const int w    = tid >> 6;           // 0..7
    const int g    = blockIdx.x;

    // ---- consumers only: prefetch own 4 V/F rows (64 KB) at t=0 ----
    float4 pf[8];
    if (g >= BB) {
        const int r = w >> 1, m = w & 1;
        const float4* __restrict__ src =
            (const float4*)((m ? Fm : Vm) + (size_t)(4 * g + r) * DD);
#pragma unroll
        for (int k = 0; k < 8; ++k) pf[k] = src[k * 64 + lane];
    }

    // ---- producer: phase1 for batch b0 = g (verified R7/R8 path) ----
    if (g < BB) {
        const int b0 = g;
        const int4 zt = ((const int4*)(z + (size_t)b0 * HH))[DG4 - 1];
        const int d1 = zt.w;          // z[H-1]     in [0, NN)
        const int d2 = zt.z + NN;     // z[H-2]+NN  in [NN, DD)

        const int4 zv = ((const int4*)(z + (size_t)b0 * HH))[tid];  // h = 4t..4t+3
        float4 wa = ((const float4*)(Wm + (size_t)d1 * DD))[tid];
        float4 wc = ((const float4*)(Wm + (size_t)d2 * DD))[tid];

        ((int4*)zsh)[tid] = zv;
        float4 uu;
        uu.x = wa.x + wc.x; uu.y = wa.y + wc.y;
        uu.z = wa.z + wc.z; uu.w = wa.w + wc.w;
        ((float4*)u)[tid] = uu;
        ((float4*)wsf)[tid] = make_float4(0.f, 0.f, 0.f, 0.f);
        __syncthreads();                                    // A

        const int zp0 = (tid > 0) ? zsh[4 * tid - 1] + NN : 0;
        const float s0 = u[zv.x] + ((tid > 0) ? u[zp0] : 0.f);
        const float s1 = u[zv.y] + u[zv.x + NN];
        const float s2 = u[zv.z] + u[zv.y + NN];
        const float s3 = u[zv.w] + u[zv.z + NN];

        // |s| < 0.5 -> exp without max subtraction is softmax-identical
        const float e0 = __expf(s0);
        const float e1 = __expf(s1);
        const float e2 = __expf(s2);
        const float e3 = __expf(s3);
        float t = (e0 + e1) + (e2 + e3);
#pragma unroll
        for (int off = 32; off > 0; off >>= 1) t += __shfl_xor(t, off);
        if (lane == 0) redt[w] = t;

        atomicAdd(&wsf[zv.x], e0);
        if (tid > 0) atomicAdd(&wsf[zp0], e0);
        atomicAdd(&wsf[zv.y], e1); atomicAdd(&wsf[zv.x + NN], e1);
        atomicAdd(&wsf[zv.z], e2); atomicAdd(&wsf[zv.y + NN], e2);
        atomicAdd(&wsf[zv.w], e3); atomicAdd(&wsf[zv.z + NN], e3);
        __syncthreads();                                    // B

        float tot = redt[0];
#pragma unroll
        for (int i = 1; i < 8; ++i) tot += redt[i];
        const float inv = 1.f / tot;

        const unsigned lo = (unsigned)f2bf(wsf[4 * tid + 0] * inv)
                          | ((unsigned)f2bf(wsf[4 * tid + 1] * inv) << 16);
        const unsigned hi = (unsigned)f2bf(wsf[4 * tid + 2] * inv)
                          | ((unsigned)f2bf(wsf[4 * tid + 3] * inv) << 16);
        const unsigned long long pk =
            (unsigned long long)lo | ((unsigned long long)hi << 32);
        __hip_atomic_store(&wsB[(size_t)tid * BB + b0], pk,
                           __ATOMIC_RELAXED, __HIP_MEMORY_SCOPE_AGENT);
        if (tid == 0) {
            __hip_atomic_store(&hdr[b0], d1, __ATOMIC_RELAXED, __HIP_MEMORY_SCOPE_AGENT);
            __hip_atomic_store(&hdr[BB + b0], d2, __ATOMIC_RELAXED, __HIP_MEMORY_SCOPE_AGENT);
        }
        __syncthreads();   // all threads' stores drained before release
        if (tid == 0)
            __hip_atomic_fetch_add(flag, 1u, __ATOMIC_RELEASE, __HIP_MEMORY_SCOPE_AGENT);
    }

    // ---- spin until all 16 producers published (bounded) ----
    if (tid == 0) {
        int budget = 1 << 17;
        while (__hip_atomic_load(flag, __ATOMIC_ACQUIRE, __HIP_MEMORY_SCOPE_AGENT) < BB
               && --budget) {
            __builtin_amdgcn_s_sleep(8);
        }
    }
    __syncthreads();

    // keep consumer prefetch alive (prevent DCE)
    if (g >= BB) {
#pragma unroll
        for (int k = 0; k < 8; ++k)
            asm volatile("" :: "v"(pf[k].x), "v"(pf[k].y), "v"(pf[k].z), "v"(pf[k].w));
    }

    // ---- consumer: rows 4g..4g+3 for all 16 batches (verified dot) ----
    const int b = lane & 15;
    const int s = tid >> 4;              // 0..31

    unsigned long long wsr[16];
#pragma unroll
    for (int i = 0; i < 16; ++i)
        wsr[i] = __hip_atomic_load(&wsB[(size_t)(s + 32 * i) * BB + b],
                                   __ATOMIC_RELAXED, __HIP_MEMORY_SCOPE_AGENT);

    const float4* __restrict__ Vr0 = (const float4*)(Vm + (size_t)(4 * g + 0) * DD);
    const float4* __restrict__ Vr1 = (const float4*)(Vm + (size_t)(4 * g + 1) * DD);
    const float4* __restrict__ Vr2 = (const float4*)(Vm + (size_t)(4 * g + 2) * DD);
    const float4* __restrict__ Vr3 = (const float4*)(Vm + (size_t)(4 * g + 3) * DD);
    const float4* __restrict__ Fr0 = (const float4*)(Fm + (size_t)(4 * g + 0) * DD);
    const float4* __restrict__ Fr1 = (const float4*)(Fm + (size_t)(4 * g + 1) * DD);
    const float4* __restrict__ Fr2 = (const float4*)(Fm + (size_t)(4 * g + 2) * DD);
    const float4* __restrict__ Fr3 = (const float4*)(Fm + (size_t)(4 * g + 3) * DD);

    float acc[8];
#pragma unroll
    for (int j = 0; j < 8; ++j) acc[j] = 0.f;

#pragma unroll
    for (int it = 0; it < 16; ++it) {
        const int dg = s + 32 * it;
        const unsigned px = (unsigned)wsr[it];
        const unsigned py = (unsigned)(wsr[it] >> 32);
        const float s0 = __uint_as_float(px << 16);
        const float s1 = __uint_as_float(px & 0xffff0000u);
        const float s2 = __uint_as_float(py << 16);
        const float s3 = __uint_as_float(py & 0xffff0000u);
        float4 v0 = Vr0[dg], v1 = Vr1[dg], v2 = Vr2[dg], v3 = Vr3[dg];
        float4 f0 = Fr0[dg], f1 = Fr1[dg], f2 = Fr2[dg], f3 = Fr3[dg];
        acc[0] += v0.x * s0 + v0.y * s1 + v0.z * s2 + v0.w * s3;
        acc[1] += f0.x * s0 + f0.y * s1 + f0.z * s2 + f0.w * s3;
        acc[2] += v1.x * s0 + v1.y * s1 + v1.z * s2 + v1.w * s3;
        acc[3] += f1.x * s0 + f1.y * s1 + f1.z * s2 + f1.w * s3;
        acc[4] += v2.x * s0 + v2.y * s1 + v2.z * s2 + v2.w * s3;
        acc[5] += f2.x * s0 + f2.y * s1 + f2.z * s2 + f2.w * s3;
        acc[6] += v3.x * s0 + v3.y * s1 + v3.z * s2 + v3.w * s3;
        acc[7] += f3.x * s0 + f3.y * s1 + f3.z * s2 + f3.w * s3;
    }

#pragma unroll
    for (int j = 0; j < 8; ++j) {
        float p = acc[j];
        p += __shfl_xor(p, 16);
        p += __shfl_xor(p, 32);
        acc[j] = p;
    }

    if (lane < 16) {
#pragma unroll
        for (int j = 0; j < 8; ++j) red[j][w][b] = acc[j];
    }
    __syncthreads();

    if (tid < 64) {
        const int r = tid >> 4, bb = tid & 15;
        float A = 0.f, Fv = 0.f;
#pragma unroll
        for (int ww = 0; ww < 8; ++ww) {
            A  += red[2 * r + 0][ww][bb];
            Fv += red[2 * r + 1][ww][bb];
        }
        const int n = 4 * g + r;
        const int e1i = __hip_atomic_load(&hdr[bb],      __ATOMIC_RELAXED, __HIP_MEMORY_SCOPE_AGENT);
        const int e2i = __hip_atomic_load(&hdr[BB + bb], __ATOMIC_RELAXED, __HIP_MEMORY_SCOPE_AGENT);
        const float* __restrict__ Fr = Fm + (size_t)n * DD;
        Fv += Fr[e1i] + Fr[e2i];
        out[(size_t)bb * NN + n]            = A + Fv;   // xi
        out[(size_t)(BB + bb) * NN + n]     = A;        // xi_A
        out[(size_t)(2 * BB + bb) * NN + n] = Fv;       // xi_F
    }
}

extern "C" void kernel_launch(void* const* d_in, const int* in_sizes, int n_in,
                              void* d_out, int out_size, void* d_ws, size_t ws_size,
                              hipStream_t stream) {
    const int*   z  = (const int*)d_in[0];
    const float* Fm = (const float*)d_in[1];
    const float* Vm = (const float*)d_in[2];
    const float* Wm = (const float*)d_in[3];
    float* out = (float*)d_out;

    unsigned* flag = (unsigned*)d_ws;
    int*      hdr  = (int*)((char*)d_ws + 128);
    unsigned long long* wsB = (unsigned long long*)((char*)d_ws + 256);

    hipMemsetAsync(flag, 0, sizeof(unsigned), stream);
    ot_one<<<256, 512, 0, stream>>>(z, Fm, Vm, Wm, flag, hdr, wsB, out);
}

// Round 10
// 23.761 us; speedup vs baseline: 1.5682x; 1.5682x over previous
//
#include <hip/hip_runtime.h>

#define BB 16
#define HH 2048
#define NN 1024
#define DD 2048
#define DG4 (DD / 4)   // 512 float4-groups per row

// Workspace: int hdr[32] (d1[16], d2[16]); pad to 128 B; then
// wsB[DG4][BB] uint2 — 4 consecutive d packed as bf16x4 per batch (64 KB).

__device__ __forceinline__ unsigned short f2bf(float f) {
    unsigned u = __float_as_uint(f);
    u += 0x7fffu + ((u >> 16) & 1u);   // round-to-nearest-even
    return (unsigned short)(u >> 16);
}

// Kernel 1: 256 blocks x 512 threads.
//  - Consumer blocks (g>=16) warm-read their 4 V/F rows at t=0 (pulls 15 MB
//    into L2/L3 concurrently with phase1; kept live via empty asm).
//  - Blocks 0..15 run phase1 for batch b = g with a CLEAN critical path
//    (no competing prefetch before barrier A), then warm their rows after.
__global__ __launch_bounds__(512) void ot_p1warm(const int* __restrict__ z,
                                                 const float* __restrict__ Fm,
                                                 const float* __restrict__ Vm,
                                                 const float* __restrict__ Wm,
                                                 int* __restrict__ hdr,
                                                 uint2* __restrict__ wsB) {
    __shared__ int   zsh[HH];
    __shared__ float u[DD];
    __shared__ float wsf[DD];
    __shared__ float redt[8];

    const int tid  = threadIdx.x;
    const int lane = tid & 63;
    const int w    = tid >> 6;
    const int g    = blockIdx.x;

    const int r = w >> 1, m = w & 1;
    const float4* __restrict__ rowsrc =
        (const float4*)((m ? Fm : Vm) + (size_t)(4 * g + r) * DD);

    float4 pf[8];
    if (g >= BB) {
        // consumers: warm reads issued first (HBM stream overlaps phase1)
#pragma unroll
        for (int k = 0; k < 8; ++k) pf[k] = rowsrc[k * 64 + lane];
    } else {
        const int b = g;
        // z tail -> d1,d2 (broadcast load, no barrier needed)
        const int4 zt = ((const int4*)(z + (size_t)b * HH))[DG4 - 1];
        const int d1 = zt.w;          // z[H-1]     in [0, NN)
        const int d2 = zt.z + NN;     // z[H-2]+NN  in [NN, DD)

        // issue z row + both W rows
        const int4 zv = ((const int4*)(z + (size_t)b * HH))[tid];   // h = 4t..4t+3
        float4 wa = ((const float4*)(Wm + (size_t)d1 * DD))[tid];
        float4 wc = ((const float4*)(Wm + (size_t)d2 * DD))[tid];

        ((int4*)zsh)[tid] = zv;
        float4 uu;
        uu.x = wa.x + wc.x; uu.y = wa.y + wc.y;
        uu.z = wa.z + wc.z; uu.w = wa.w + wc.w;
        ((float4*)u)[tid] = uu;
        ((float4*)wsf)[tid] = make_float4(0.f, 0.f, 0.f, 0.f);
        __syncthreads();                                    // A

        const int zp0 = (tid > 0) ? zsh[4 * tid - 1] + NN : 0;
        const float s0 = u[zv.x] + ((tid > 0) ? u[zp0] : 0.f);
        const float s1 = u[zv.y] + u[zv.x + NN];
        const float s2 = u[zv.z] + u[zv.y + NN];
        const float s3 = u[zv.w] + u[zv.z + NN];

        // exp without max subtraction (|s| < 0.5): softmax-identical
        const float e0 = __expf(s0);
        const float e1 = __expf(s1);
        const float e2 = __expf(s2);
        const float e3 = __expf(s3);
        float t = (e0 + e1) + (e2 + e3);
#pragma unroll
        for (int off = 32; off > 0; off >>= 1) t += __shfl_xor(t, off);
        if (lane == 0) redt[w] = t;

        // scatter unnormalized weights
        atomicAdd(&wsf[zv.x], e0);
        if (tid > 0) atomicAdd(&wsf[zp0], e0);
        atomicAdd(&wsf[zv.y], e1); atomicAdd(&wsf[zv.x + NN], e1);
        atomicAdd(&wsf[zv.z], e2); atomicAdd(&wsf[zv.y + NN], e2);
        atomicAdd(&wsf[zv.w], e3); atomicAdd(&wsf[zv.z + NN], e3);
        __syncthreads();                                    // B

        float tot = redt[0];
#pragma unroll
        for (int i = 1; i < 8; ++i) tot += redt[i];
        const float inv = 1.f / tot;

        // pack bf16x4 per d-group, layout [dg][b]
        uint2 p;
        p.x = (unsigned)f2bf(wsf[4 * tid + 0] * inv)
            | ((unsigned)f2bf(wsf[4 * tid + 1] * inv) << 16);
        p.y = (unsigned)f2bf(wsf[4 * tid + 2] * inv)
            | ((unsigned)f2bf(wsf[4 * tid + 3] * inv) << 16);
        wsB[(size_t)tid * BB + b] = p;
        if (tid == 0) { hdr[b] = d1; hdr[BB + b] = d2; }

        // now warm this block's own rows (overlaps k1 tail / k2 launch)
#pragma unroll
        for (int k = 0; k < 8; ++k) pf[k] = rowsrc[k * 64 + lane];
    }

    // keep warm loads alive (prevent DCE / load narrowing)
#pragma unroll
    for (int k = 0; k < 8; ++k)
        asm volatile("" :: "v"(pf[k].x), "v"(pf[k].y), "v"(pf[k].z), "v"(pf[k].w));
}

// Kernel 2 (verified R5/R7): block g computes rows n = 4g..4g+3 for all
// 16 batches. Thread (s = tid>>4 in 0..31, b = tid&15); ws packed in 32 VGPRs.
__global__ __launch_bounds__(512, 4) void ot_phase2(const float* __restrict__ V,
                                                    const float* __restrict__ F,
                                                    const int* __restrict__ hdr,
                                                    const uint2* __restrict__ wsB,
                                                    float* __restrict__ out) {
    const int tid  = threadIdx.x;
    const int lane = tid & 63;
    const int w    = tid >> 6;
    const int b    = lane & 15;
    const int s    = tid >> 4;            // 0..31
    const int g    = blockIdx.x;

    uint2 wsr[16];
#pragma unroll
    for (int i = 0; i < 16; ++i) wsr[i] = wsB[(size_t)(s + 32 * i) * BB + b];

    const float4* __restrict__ Vr0 = (const float4*)(V + (size_t)(4 * g + 0) * DD);
    const float4* __restrict__ Vr1 = (const float4*)(V + (size_t)(4 * g + 1) * DD);
    const float4* __restrict__ Vr2 = (const float4*)(V + (size_t)(4 * g + 2) * DD);
    const float4* __restrict__ Vr3 = (const float4*)(V + (size_t)(4 * g + 3) * DD);
    const float4* __restrict__ Fr0 = (const float4*)(F + (size_t)(4 * g + 0) * DD);
    const float4* __restrict__ Fr1 = (const float4*)(F + (size_t)(4 * g + 1) * DD);
    const float4* __restrict__ Fr2 = (const float4*)(F + (size_t)(4 * g + 2) * DD);
    const float4* __restrict__ Fr3 = (const float4*)(F + (size_t)(4 * g + 3) * DD);

    float acc[8];
#pragma unroll
    for (int j = 0; j < 8; ++j) acc[j] = 0.f;

#pragma unroll
    for (int it = 0; it < 16; ++it) {
        const int dg = s + 32 * it;
        const uint2 p = wsr[it];
        const float s0 = __uint_as_float(p.x << 16);
        const float s1 = __uint_as_float(p.x & 0xffff0000u);
        const float s2 = __uint_as_float(p.y << 16);
        const float s3 = __uint_as_float(p.y & 0xffff0000u);
        float4 v0 = Vr0[dg], v1 = Vr1[dg], v2 = Vr2[dg], v3 = Vr3[dg];
        float4 f0 = Fr0[dg], f1 = Fr1[dg], f2 = Fr2[dg], f3 = Fr3[dg];
        acc[0] += v0.x * s0 + v0.y * s1 + v0.z * s2 + v0.w * s3;
        acc[1] += f0.x * s0 + f0.y * s1 + f0.z * s2 + f0.w * s3;
        acc[2] += v1.x * s0 + v1.y * s1 + v1.z * s2 + v1.w * s3;
        acc[3] += f1.x * s0 + f1.y * s1 + f1.z * s2 + f1.w * s3;
        acc[4] += v2.x * s0 + v2.y * s1 + v2.z * s2 + v2.w * s3;
        acc[5] += f2.x * s0 + f2.y * s1 + f2.z * s2 + f2.w * s3;
        acc[6] += v3.x * s0 + v3.y * s1 + v3.z * s2 + v3.w * s3;
        acc[7] += f3.x * s0 + f3.y * s1 + f3.z * s2 + f3.w * s3;
    }

#pragma unroll
    for (int j = 0; j < 8; ++j) {
        float p = acc[j];
        p += __shfl_xor(p, 16);
        p += __shfl_xor(p, 32);
        acc[j] = p;
    }

    __shared__ float red[8][8][BB];
    if (lane < 16) {
#pragma unroll
        for (int j = 0; j < 8; ++j) red[j][w][b] = acc[j];
    }
    __syncthreads();

    if (tid < 64) {
        const int r = tid >> 4, bb = tid & 15;
        float A = 0.f, Fv = 0.f;
#pragma unroll
        for (int ww = 0; ww < 8; ++ww) {
            A  += red[2 * r + 0][ww][bb];
            Fv += red[2 * r + 1][ww][bb];
        }
        const int n = 4 * g + r;
        const float* __restrict__ Fr = F + (size_t)n * DD;
        Fv += Fr[hdr[bb]] + Fr[hdr[BB + bb]];
        out[(size_t)bb * NN + n]            = A + Fv;   // xi
        out[(size_t)(BB + bb) * NN + n]     = A;        // xi_A
        out[(size_t)(2 * BB + bb) * NN + n] = Fv;       // xi_F
    }
}

extern "C" void kernel_launch(void* const* d_in, const int* in_sizes, int n_in,
                              void* d_out, int out_size, void* d_ws, size_t ws_size,
                              hipStream_t stream) {
    const int*   z  = (const int*)d_in[0];
    const float* Fm = (const float*)d_in[1];
    const float* Vm = (const float*)d_in[2];
    const float* Wm = (const float*)d_in[3];
    float* out = (float*)d_out;

    int*   hdr = (int*)d_ws;
    uint2* wsB = (uint2*)((char*)d_ws + 128);

    ot_p1warm<<<256, 512, 0, stream>>>(z, Fm, Vm, Wm, hdr, wsB);
    ot_phase2<<<NN / 4, 512, 0, stream>>>(Vm, Fm, hdr, wsB, out);
}